// Round 8
// baseline (243.321 us; speedup 1.0000x reference)
//
#include <hip/hip_runtime.h>

// Pipeline:
//  1) cvt_all: query,key,Wq,Wk,Wv f32 -> bf16 (single launch)
//  2) gemm8p: all 3 projections, one dispatch (768 blocks). 256x256 tile, BK=64,
//     8 waves, 8x16KB LDS subtile slots, 8-phase counted-vmcnt schedule:
//     per phase {ds_read frags | stage 1 subtile of tile t+1 | vmcnt(4) | s_barrier |
//     setprio(1) 16 MFMA setprio(0) | s_barrier}. vmcnt never drains to 0 in the loop.
//  3) chunk_sums (MFMA): per (nh,chunk): ST[e][d] = sum_s V[s][e]K[s][d] (bf16), z[d] (f32)
//  4) scan_chunks: exclusive prefix over chunks (bf16 payload, f32 accum; z f32)
//  5) attn_out: per (nh,chunk): A=tril(QK^T); out = (A V + Q S_prev) / (rowsum(A) + Q z_prev)

using bf16x8 = __attribute__((ext_vector_type(8))) short;
using u16x8  = __attribute__((ext_vector_type(8))) unsigned short;
using f32x4  = __attribute__((ext_vector_type(4))) float;

#define L_SEQ   8192
#define NCHUNK  128
#define RECB    8448   // bytes: 4096 bf16 ST + 64 f32 z

__device__ __forceinline__ float bf2f(unsigned short u) {
  union { unsigned int i; float f; } c; c.i = ((unsigned int)u) << 16; return c.f;
}
__device__ __forceinline__ unsigned short f2bf(float f) {
  union { float f; unsigned int i; } c; c.f = f;
  unsigned int r = c.i + 0x7fffu + ((c.i >> 16) & 1u);
  return (unsigned short)(r >> 16);
}
__device__ __forceinline__ float sp_(float x) {
  return (x > 20.0f) ? x : __logf(1.0f + __expf(x));
}
__device__ __forceinline__ void gll16(const void* g, void* l) {
  __builtin_amdgcn_global_load_lds(
      (const __attribute__((address_space(1))) unsigned int*)g,
      (__attribute__((address_space(3))) unsigned int*)l, 16, 0, 0);
}

// segment boundaries in float4 units:
//   q  [0,        4194304)
//   k  [4194304,  8388608)
//   wq [8388608,  8454144)   : 512*512/4 = 65536 float4 each
//   wk [8454144,  8519680)
//   wv [8519680,  8585216)
__global__ void cvt_all(const float* __restrict__ q, const float* __restrict__ k,
                        const float* __restrict__ wq, const float* __restrict__ wk,
                        const float* __restrict__ wv,
                        unsigned short* __restrict__ qo, unsigned short* __restrict__ ko,
                        unsigned short* __restrict__ wqo, unsigned short* __restrict__ wko,
                        unsigned short* __restrict__ wvo) {
  const int stride = gridDim.x * blockDim.x;
  for (int i = blockIdx.x * blockDim.x + threadIdx.x; i < 8585216; i += stride) {
    const float* src; unsigned short* dst; int off;
    if (i < 4194304)      { src = q;  dst = qo;  off = i; }
    else if (i < 8388608) { src = k;  dst = ko;  off = i - 4194304; }
    else if (i < 8454144) { src = wq; dst = wqo; off = i - 8388608; }
    else if (i < 8519680) { src = wk; dst = wko; off = i - 8454144; }
    else                  { src = wv; dst = wvo; off = i - 8519680; }
    float4 v = ((const float4*)src)[off];
    ushort4 o;
    o.x = f2bf(v.x); o.y = f2bf(v.y); o.z = f2bf(v.z); o.w = f2bf(v.w);
    ((ushort4*)dst)[off] = o;
  }
}

// quarter-swizzle within a 64B k-half row: 2-way residual bank aliasing only
#define SWZR(r) ((((r) & 3) ^ (((r) >> 2) & 3)))

// C[m][n] = sum_k A[m][k]*W[n][k]; per sub-GEMM M=32768, N=K=512.
// 256x256 tile, BK=64, 8 waves (2M x 4N), per-wave 128x64, acc[8][4].
// LDS: 8 subtile slots x 16KB (subtile = 256 rows x 32 k-cols of A or B).
// Subtile position stream: pos 4t+{0,1,2,3} = {A-k0, B-k0, A-k1, B-k1}(tile t),
// slot = pos&7. Phase g (=4t+p) stages pos g+4, waits vmcnt(4) -> pos<=g+2 landed.
__global__ __launch_bounds__(512, 1) void gemm8p(const unsigned short* __restrict__ qbf,
                                                 const unsigned short* __restrict__ kbf,
                                                 const unsigned short* __restrict__ wqb,
                                                 const unsigned short* __restrict__ wkb,
                                                 const unsigned short* __restrict__ wvb,
                                                 unsigned short* __restrict__ qb,
                                                 unsigned short* __restrict__ kb,
                                                 unsigned short* __restrict__ vt) {
  __shared__ char Lds[131072];
  const int raw = blockIdx.x;
  const int wg  = (raw & 7) * 96 + (raw >> 3);   // bijective XCD swizzle (768 = 8*96)
  const int sub = wg >> 8;
  const int b   = wg & 255;
  const int bm  = (b >> 1) * 256;
  const int bn  = (b & 1) * 256;

  const unsigned short* A; const unsigned short* W; unsigned short* outp; int mode;
  if (sub == 0)      { A = qbf; W = wqb; outp = qb; mode = 0; }
  else if (sub == 1) { A = kbf; W = wkb; outp = kb; mode = 0; }
  else               { A = kbf; W = wvb; outp = vt; mode = 1; }
  const char* Abytes = (const char*)A;
  const char* Wbytes = (const char*)W;

  const int tid = threadIdx.x, lane = tid & 63, wid = tid >> 6;
  const int l15 = lane & 15, lg = lane >> 4;
  const int wm = wid >> 2, wn = wid & 3;

  f32x4 acc[8][4] = {};
  bf16x8 bC[4];

// stage one 16KB subtile (type base/rowbase, tile tt, k-half h) into slot sl.
// LDS dest linear (wave-uniform base + lane*16); global source pre-swizzled.
#define STG(base, rowbase, tt, h, sl)                                              \
  { _Pragma("unroll")                                                              \
    for (int s_ = 0; s_ < 2; ++s_) {                                               \
      const int r_ = s_ * 128 + (tid >> 2);                                        \
      const int c_ = ((tid & 3) ^ SWZR(r_)) << 4;                                  \
      gll16(base + (size_t)(rowbase + r_) * 1024 + (tt) * 128 + (h) * 64 + c_,     \
            Lds + (sl) * 16384 + s_ * 8192 + wid * 1024);                          \
    } }

// read one MFMA fragment (16B) from slot sl, logical row, this lane's k-quarter
#define LDF(sl, row) \
  (*(const bf16x8*)(Lds + (sl) * 16384 + (row) * 64 + ((lg ^ SWZR(row)) << 4)))

// phase P (0..3) of tile t: bs = base slot of tile t (0 or 4), ns = other group.
// P&1 = mi-half, P>>1 = k-half. Stages subtile P of tile t+1 (unless LASTT).
#define PHASE(bs, ns, t, P, LASTT)                                                    \
  {                                                                                   \
    constexpr int mh_ = (P) & 1, kh_ = (P) >> 1;                                      \
    bf16x8 af[4];                                                                     \
    _Pragma("unroll")                                                                 \
    for (int mi = 0; mi < 4; ++mi)                                                    \
      af[mi] = LDF((bs) + kh_ * 2, wm * 128 + mh_ * 64 + mi * 16 + l15);              \
    if (mh_ == 0) {                                                                   \
      _Pragma("unroll")                                                               \
      for (int ni = 0; ni < 4; ++ni)                                                  \
        bC[ni] = LDF((bs) + kh_ * 2 + 1, wn * 64 + ni * 16 + l15);                    \
    }                                                                                 \
    if (!(LASTT)) {                                                                   \
      if (mh_) { STG(Wbytes, bn, (t) + 1, kh_, (ns) + kh_ * 2 + 1); }                 \
      else     { STG(Abytes, bm, (t) + 1, kh_, (ns) + kh_ * 2); }                     \
    }                                                                                 \
    if ((LASTT) && (P) == 0) { asm volatile("s_waitcnt vmcnt(0)" ::: "memory"); }     \
    else                     { asm volatile("s_waitcnt vmcnt(4)" ::: "memory"); }     \
    __builtin_amdgcn_s_barrier();                                                     \
    __builtin_amdgcn_s_setprio(1);                                                    \
    _Pragma("unroll")                                                                 \
    for (int mi = 0; mi < 4; ++mi)                                                    \
      _Pragma("unroll")                                                               \
      for (int ni = 0; ni < 4; ++ni)                                                  \
        acc[mh_ * 4 + mi][ni] =                                                       \
            __builtin_amdgcn_mfma_f32_16x16x32_bf16(af[mi], bC[ni],                   \
                                                    acc[mh_ * 4 + mi][ni], 0, 0, 0);  \
    __builtin_amdgcn_s_setprio(0);                                                    \
    __builtin_amdgcn_s_barrier();                                                     \
  }

  // prologue: stage tile 0 (positions 0..3), guarantee pos 0,1 before phase 0
  STG(Abytes, bm, 0, 0, 0);
  STG(Wbytes, bn, 0, 0, 1);
  STG(Abytes, bm, 0, 1, 2);
  STG(Wbytes, bn, 0, 1, 3);
  asm volatile("s_waitcnt vmcnt(4)" ::: "memory");
  __builtin_amdgcn_s_barrier();

#pragma unroll 1
  for (int t = 0; t < 6; t += 2) {
    PHASE(0, 4, t, 0, false) PHASE(0, 4, t, 1, false)
    PHASE(0, 4, t, 2, false) PHASE(0, 4, t, 3, false)
    PHASE(4, 0, t + 1, 0, false) PHASE(4, 0, t + 1, 1, false)
    PHASE(4, 0, t + 1, 2, false) PHASE(4, 0, t + 1, 3, false)
  }
  PHASE(0, 4, 6, 0, false) PHASE(0, 4, 6, 1, false)
  PHASE(0, 4, 6, 2, false) PHASE(0, 4, 6, 3, false)
  PHASE(4, 0, 7, 0, true)  PHASE(4, 0, 7, 1, true)
  PHASE(4, 0, 7, 2, true)  PHASE(4, 0, 7, 3, true)

#undef PHASE
#undef LDF
#undef STG

#pragma unroll
  for (int am = 0; am < 8; ++am)
#pragma unroll
    for (int ni = 0; ni < 4; ++ni)
#pragma unroll
      for (int j = 0; j < 4; ++j) {
        const int m = bm + wm * 128 + am * 16 + lg * 4 + j;
        const int n = bn + wn * 64 + ni * 16 + l15;
        float x = acc[am][ni][j];
        const int nb = m >> 13;
        const int l  = m & 8191;
        const int h  = n >> 6;
        if (mode == 0) {
          x = sp_(sp_(x));
          const int d = n & 63;
          outp[(((size_t)(nb * 8 + h) * 8192 + l) << 6) + d] = f2bf(x);
        } else {
          const int e = n & 63;
          const int cc = l >> 6, s = l & 63;
          outp[(((size_t)((nb * 8 + h) * 128 + cc) * 64 + e) << 6) + s] = f2bf(x);
        }
      }
}

// Per (nh, chunk): ST[e][d] = sum_s Vt[e][s]*K[s][d] via MFMA (in-LDS K transpose); z[d] = sum_s K[s][d]
__global__ __launch_bounds__(256, 4) void chunk_sums(const unsigned short* __restrict__ kb,
                                                     const unsigned short* __restrict__ vt,
                                                     char* __restrict__ S) {
  const int b  = blockIdx.x;          // nh*128 + c
  const int nh = b >> 7, c = b & 127;
  __shared__ char Kt[8192];    // [d][s] bf16, XOR-swizzled rows
  __shared__ char STs[8192];   // [e][d] bf16, linear
  const int tid = threadIdx.x, lane = tid & 63, wave = tid >> 6;
  const int l15 = lane & 15, lg = lane >> 4;
  const unsigned short* kch = kb + ((size_t)(nh * L_SEQ + c * 64) << 6);
  const unsigned short* vch = vt + ((size_t)b << 12);

  // transpose K chunk [s][d] -> Kt[d][s] (swizzled)
  {
    const int s = tid >> 2, d0 = (tid & 3) << 4;
    u16x8 a = *(const u16x8*)(kch + s * 64 + d0);
    u16x8 bb = *(const u16x8*)(kch + s * 64 + d0 + 8);
#pragma unroll
    for (int i = 0; i < 8; ++i) {
      const int d = d0 + i;
      *(unsigned short*)(Kt + d * 128 + ((2 * s) ^ ((d & 7) << 4))) = a[i];
    }
#pragma unroll
    for (int i = 0; i < 8; ++i) {
      const int d = d0 + 8 + i;
      *(unsigned short*)(Kt + d * 128 + ((2 * s) ^ ((d & 7) << 4))) = bb[i];
    }
  }
  __syncthreads();

  // MFMA: wave w -> e-rows 16w..16w+15 ; ST[e][d] = sum_s Vt[e][s]*Kt[d][s]
  f32x4 acc[4] = {};
#pragma unroll
  for (int kk = 0; kk < 2; ++kk) {
    bf16x8 av = *(const bf16x8*)(vch + (wave * 16 + l15) * 64 + kk * 32 + lg * 8);
#pragma unroll
    for (int ni = 0; ni < 4; ++ni) {
      const int d = ni * 16 + l15;
      bf16x8 bk = *(const bf16x8*)(Kt + d * 128 + ((kk * 64 + lg * 16) ^ ((d & 7) << 4)));
      acc[ni] = __builtin_amdgcn_mfma_f32_16x16x32_bf16(av, bk, acc[ni], 0, 0, 0);
    }
  }

  char* rec = S + (size_t)b * RECB;

  // z[d] = sum_s K[s][d] from Kt rows (f32)
  if (tid < 64) {
    float z = 0.f;
#pragma unroll
    for (int kk = 0; kk < 8; ++kk) {
      bf16x8 kv = *(const bf16x8*)(Kt + tid * 128 + ((kk * 16) ^ ((tid & 7) << 4)));
#pragma unroll
      for (int i = 0; i < 8; ++i) z += bf2f(kv[i]);
    }
    *(float*)(rec + 8192 + tid * 4) = z;
  }

  // stage ST to LDS (bf16), then coalesced copy-out
#pragma unroll
  for (int ni = 0; ni < 4; ++ni)
#pragma unroll
    for (int j = 0; j < 4; ++j) {
      const int e = wave * 16 + lg * 4 + j, d = ni * 16 + l15;
      *(unsigned short*)(STs + e * 128 + d * 2) = f2bf(acc[ni][j]);
    }
  __syncthreads();
  {
    const int off = tid * 32;
    *(u16x8*)(rec + off)      = *(const u16x8*)(STs + off);
    *(u16x8*)(rec + off + 16) = *(const u16x8*)(STs + off + 16);
  }
}

// Exclusive prefix over 128 chunks, in place. ST: bf16 payload, f32 accum (paired); z: f32.
__global__ void scan_chunks(char* __restrict__ S) {
  const int g = blockIdx.x * 256 + threadIdx.x;
  if (g < 65536) {                       // 32 nh * 2048 bf16-pairs
    const int nh = g >> 11, pr = g & 2047;
    char* p = S + (size_t)nh * NCHUNK * RECB + pr * 4;
    float a0 = 0.f, a1 = 0.f;
    for (int c = 0; c < NCHUNK; ++c) {
      const unsigned int u = *(unsigned int*)p;
      const float t0 = bf2f((unsigned short)(u & 0xffff));
      const float t1 = bf2f((unsigned short)(u >> 16));
      *(unsigned int*)p = (unsigned int)f2bf(a0) | ((unsigned int)f2bf(a1) << 16);
      a0 += t0; a1 += t1;
      p += RECB;
    }
  } else if (g < 67584) {                // 32 nh * 64 z floats
    const int idx = g - 65536;
    const int nh = idx >> 6, d = idx & 63;
    char* p = S + (size_t)nh * NCHUNK * RECB + 8192 + d * 4;
    float a = 0.f;
    for (int c = 0; c < NCHUNK; ++c) {
      const float t = *(float*)p; *(float*)p = a; a += t; p += RECB;
    }
  }
}

__global__ __launch_bounds__(256, 2) void attn_out(const unsigned short* __restrict__ qb,
                                                   const unsigned short* __restrict__ kb,
                                                   const unsigned short* __restrict__ vt,
                                                   const char* __restrict__ S,
                                                   float* __restrict__ out) {
  const int b  = blockIdx.x;
  const int nh = b >> 7, c = b & 127;
  const int nb = nh >> 3, h = nh & 7;
  __shared__ char Qs[8192], Ks[8192], Vs[8192], STs[8192], Ps[8192];
  __shared__ float zsh[64], dzh[64];
  const int tid = threadIdx.x, lane = tid & 63, wave = tid >> 6;
  const int l15 = lane & 15, lg = lane >> 4;

  const char* qch = (const char*)(qb + ((size_t)(nh * L_SEQ + c * 64) << 6));
  const char* kch = (const char*)(kb + ((size_t)(nh * L_SEQ + c * 64) << 6));
  const char* vch = (const char*)(vt + ((size_t)b << 12));
  const char* rb  = S + (size_t)b * RECB;

#pragma unroll
  for (int it = 0; it < 2; ++it) {
    const int p  = wave * 2048 + it * 1024 + lane * 16;
    const int r  = p >> 7;
    const int cb = (p & 127) ^ ((r & 7) << 4);
    const int src = r * 128 + cb;
    gll16(qch + src, Qs + wave * 2048 + it * 1024);
    gll16(kch + src, Ks + wave * 2048 + it * 1024);
    gll16(vch + src, Vs + wave * 2048 + it * 1024);
    gll16(rb + src,  STs + wave * 2048 + it * 1024);
  }
  if (tid < 64) zsh[tid] = *(const float*)(rb + 8192 + tid * 4);
  __syncthreads();

  // den_qz[t] = sum_d Q[t][d]*z_prev[d]
  {
    const int t = tid >> 2, p4 = tid & 3;
    float dq = 0.f;
#pragma unroll
    for (int half = 0; half < 2; ++half) {
      const int d0 = p4 * 16 + half * 8;
      const int cb = (d0 * 2) ^ ((t & 7) << 4);
      u16x8 qv = *(const u16x8*)(Qs + t * 128 + cb);
#pragma unroll
      for (int i = 0; i < 8; ++i) dq += bf2f(qv[i]) * zsh[d0 + i];
    }
    dq += __shfl_xor(dq, 1);
    dq += __shfl_xor(dq, 2);
    if (p4 == 0) dzh[t] = dq;
  }
  __syncthreads();

  // Phase 1: A = Q K^T (wave w owns rows 16w..16w+15)
  f32x4 accA[4] = {};
#pragma unroll
  for (int kk = 0; kk < 2; ++kk) {
    const int cb = kk * 64 + lg * 16;
    const int rq = wave * 16 + l15;
    bf16x8 aq = *(const bf16x8*)(Qs + rq * 128 + (cb ^ ((rq & 7) << 4)));
#pragma unroll
    for (int ni = 0; ni < 4; ++ni) {
      const int rk = ni * 16 + l15;
      bf16x8 bk = *(const bf16x8*)(Ks + rk * 128 + (cb ^ ((rk & 7) << 4)));
      accA[ni] = __builtin_amdgcn_mfma_f32_16x16x32_bf16(aq, bk, accA[ni], 0, 0, 0);
    }
  }

  // mask causal, rowsum (on bf16-rounded P for num/den consistency), write P
  float den4[4];
#pragma unroll
  for (int j = 0; j < 4; ++j) {
    const int t = wave * 16 + lg * 4 + j;
    float rs = 0.f;
#pragma unroll
    for (int ni = 0; ni < 4; ++ni) {
      const int s = ni * 16 + l15;
      const float v = (s <= t) ? accA[ni][j] : 0.f;
      const unsigned short pb = f2bf(v);
      rs += bf2f(pb);
      *(unsigned short*)(Ps + t * 128 + ((s * 2) ^ ((t & 7) << 4))) = pb;
    }
    rs += __shfl_xor(rs, 1);
    rs += __shfl_xor(rs, 2);
    rs += __shfl_xor(rs, 4);
    rs += __shfl_xor(rs, 8);
    den4[j] = rs + dzh[t];
  }
  __syncthreads();

  // Phase 2: num = P V + Q S_prev  (both B-operands bf16 rows, identical addressing)
  f32x4 accO[4] = {};
#pragma unroll
  for (int kk = 0; kk < 2; ++kk) {
    const int cb = kk * 64 + lg * 16;
    const int rp = wave * 16 + l15;
    bf16x8 ap = *(const bf16x8*)(Ps + rp * 128 + (cb ^ ((rp & 7) << 4)));
    bf16x8 aq = *(const bf16x8*)(Qs + rp * 128 + (cb ^ ((rp & 7) << 4)));
#pragma unroll
    for (int ni = 0; ni < 4; ++ni) {
      const int rv = ni * 16 + l15;
      bf16x8 bv = *(const bf16x8*)(Vs + rv * 128 + (cb ^ ((rv & 7) << 4)));
      bf16x8 bs = *(const bf16x8*)(STs + rv * 128 + (cb ^ ((rv & 7) << 4)));
      accO[ni] = __builtin_amdgcn_mfma_f32_16x16x32_bf16(ap, bv, accO[ni], 0, 0, 0);
      accO[ni] = __builtin_amdgcn_mfma_f32_16x16x32_bf16(aq, bs, accO[ni], 0, 0, 0);
    }
  }

#pragma unroll
  for (int ni = 0; ni < 4; ++ni) {
    const int e = ni * 16 + l15;
#pragma unroll
    for (int j = 0; j < 4; ++j) {
      const int t = wave * 16 + lg * 4 + j;
      out[((size_t)(nb * L_SEQ + c * 64 + t) << 9) + h * 64 + e] = accO[ni][j] / den4[j];
    }
  }
}

extern "C" void kernel_launch(void* const* d_in, const int* in_sizes, int n_in,
                              void* d_out, int out_size, void* d_ws, size_t ws_size,
                              hipStream_t stream) {
  (void)in_sizes; (void)n_in; (void)out_size; (void)ws_size;
  const float* query = (const float*)d_in[0];
  const float* key   = (const float*)d_in[1];
  const float* Wq    = (const float*)d_in[2];
  const float* Wk    = (const float*)d_in[3];
  const float* Wv    = (const float*)d_in[4];
  float* out = (float*)d_out;
  char* ws = (char*)d_ws;

  unsigned short* qb  = (unsigned short*)(ws);              // 33,554,432 B  (nh,l,d) bf16
  unsigned short* kb  = (unsigned short*)(ws + 33554432);   // 33,554,432 B
  unsigned short* vt  = (unsigned short*)(ws + 67108864);   // 33,554,432 B  (nh,c,e,s) bf16
  unsigned short* qbf = (unsigned short*)(ws + 100663296);  // 33,554,432 B  (dead after GEMMs)
  unsigned short* kbf = (unsigned short*)(ws + 134217728);  // 33,554,432 B  (dead after GEMMs)
  char*           Ssum = ws + 100663296;                    // 34,603,008 B  (aliased over qbf/kbf)
  unsigned short* wqb = (unsigned short*)(ws + 168820736);
  unsigned short* wkb = (unsigned short*)(ws + 169345024);
  unsigned short* wvb = (unsigned short*)(ws + 169869312);  // end: 170,393,600 B

  cvt_all<<<dim3(2048), dim3(256), 0, stream>>>(query, key, Wq, Wk, Wv, qbf, kbf, wqb, wkb, wvb);

  gemm8p<<<dim3(768), dim3(512), 0, stream>>>(qbf, kbf, wqb, wkb, wvb, qb, kb, vt);

  chunk_sums<<<dim3(4096), dim3(256), 0, stream>>>(kb, vt, Ssum);
  scan_chunks<<<dim3(264), dim3(256), 0, stream>>>(Ssum);
  attn_out<<<dim3(4096), dim3(256), 0, stream>>>(qb, kb, vt, Ssum, out);
}

// Round 9
// 208.216 us; speedup vs baseline: 1.1686x; 1.1686x over previous
//
#include <hip/hip_runtime.h>

// Pipeline:
//  1) cvt_all: query,key,Wq,Wk,Wv f32 -> bf16 (single launch)
//  2) gemm_proj<MODE> x3 (R3 champion structure): 128x128 tile, BK=64, 4 waves,
//     single-buffered 32KB LDS, stage->sync->compute->sync, ~4 blocks/CU.
//     Compute phase uses 32x32x16 MFMA (half the instruction count of 16x16x32).
//  3) chunk_sums (MFMA): per (nh,chunk): ST[e][d] = sum_s V[s][e]K[s][d] (bf16), z[d] (f32)
//  4) scan_chunks: exclusive prefix over chunks (bf16 payload, f32 accum; z f32)
//  5) attn_out: per (nh,chunk): A=tril(QK^T); out = (A V + Q S_prev) / (rowsum(A) + Q z_prev)

using bf16x8 = __attribute__((ext_vector_type(8))) short;
using u16x8  = __attribute__((ext_vector_type(8))) unsigned short;
using f32x4  = __attribute__((ext_vector_type(4))) float;
using f32x16 = __attribute__((ext_vector_type(16))) float;

#define L_SEQ   8192
#define NCHUNK  128
#define RECB    8448   // bytes: 4096 bf16 ST + 64 f32 z

__device__ __forceinline__ float bf2f(unsigned short u) {
  union { unsigned int i; float f; } c; c.i = ((unsigned int)u) << 16; return c.f;
}
__device__ __forceinline__ unsigned short f2bf(float f) {
  union { float f; unsigned int i; } c; c.f = f;
  unsigned int r = c.i + 0x7fffu + ((c.i >> 16) & 1u);
  return (unsigned short)(r >> 16);
}
__device__ __forceinline__ float sp_(float x) {
  return (x > 20.0f) ? x : __logf(1.0f + __expf(x));
}
__device__ __forceinline__ void gll16(const void* g, void* l) {
  __builtin_amdgcn_global_load_lds(
      (const __attribute__((address_space(1))) unsigned int*)g,
      (__attribute__((address_space(3))) unsigned int*)l, 16, 0, 0);
}

// segment boundaries in float4 units:
//   q  [0,        4194304)
//   k  [4194304,  8388608)
//   wq [8388608,  8454144)   : 512*512/4 = 65536 float4 each
//   wk [8454144,  8519680)
//   wv [8519680,  8585216)
__global__ void cvt_all(const float* __restrict__ q, const float* __restrict__ k,
                        const float* __restrict__ wq, const float* __restrict__ wk,
                        const float* __restrict__ wv,
                        unsigned short* __restrict__ qo, unsigned short* __restrict__ ko,
                        unsigned short* __restrict__ wqo, unsigned short* __restrict__ wko,
                        unsigned short* __restrict__ wvo) {
  const int stride = gridDim.x * blockDim.x;
  for (int i = blockIdx.x * blockDim.x + threadIdx.x; i < 8585216; i += stride) {
    const float* src; unsigned short* dst; int off;
    if (i < 4194304)      { src = q;  dst = qo;  off = i; }
    else if (i < 8388608) { src = k;  dst = ko;  off = i - 4194304; }
    else if (i < 8454144) { src = wq; dst = wqo; off = i - 8388608; }
    else if (i < 8519680) { src = wk; dst = wko; off = i - 8454144; }
    else                  { src = wv; dst = wvo; off = i - 8519680; }
    float4 v = ((const float4*)src)[off];
    ushort4 o;
    o.x = f2bf(v.x); o.y = f2bf(v.y); o.z = f2bf(v.z); o.w = f2bf(v.w);
    ((ushort4*)dst)[off] = o;
  }
}

// C[m][n] = sum_k A[m][k]*W[n][k]; M=32768, N=K=512. 128x128 tile, BK=64, 4 waves,
// per-wave 64x64 via 2x2 of 32x32x16 MFMA (acc 2x2xf32x16 = 64 AGPR).
// Single-buffered 32KB LDS, stage->sync->compute->sync (R3-proven), ~4 blocks/CU.
template <int MODE>  // 0: sp(sp(.)) -> qk layout (nh,l,d) ; 1: plain -> vt layout (nh,c,e,s)
__global__ __launch_bounds__(256, 4) void gemm_proj(const unsigned short* __restrict__ A,
                                                    const unsigned short* __restrict__ W,
                                                    unsigned short* __restrict__ out) {
  __shared__ char As[16384];
  __shared__ char Bs[16384];
  const int tid  = threadIdx.x;
  const int lane = tid & 63;
  const int wave = tid >> 6;
  const int l31  = lane & 31;
  const int hi   = lane >> 5;          // k-half selector for 32x32x16 frags
  const int wr   = (wave >> 1) * 64;
  const int wc   = (wave & 1) * 64;
  const int bm   = blockIdx.x * 128;
  const int bn   = blockIdx.y * 128;
  const char* Abytes = (const char*)A;
  const char* Wbytes = (const char*)W;

  f32x16 acc[2][2] = {};

  for (int ks = 0; ks < 8; ++ks) {
#pragma unroll
    for (int it = 0; it < 4; ++it) {
      const int p  = wave * 4096 + it * 1024 + lane * 16;
      const int r  = p >> 7;
      const int cb = (p & 127) ^ ((r & 7) << 4);   // pre-swizzled global source, linear LDS dest
      gll16(Abytes + (size_t)(bm + r) * 1024 + ks * 128 + cb, As + wave * 4096 + it * 1024);
      gll16(Wbytes + (size_t)(bn + r) * 1024 + ks * 128 + cb, Bs + wave * 4096 + it * 1024);
    }
    __syncthreads();
    // 4 k16-steps per BK=64; per step: 2 A-frags, 2 B-frags, 4 MFMA_32x32x16
#pragma unroll
    for (int s = 0; s < 4; ++s) {
      const int cb = s * 32 + hi * 16;
      bf16x8 af[2], bw[2];
#pragma unroll
      for (int mi = 0; mi < 2; ++mi) {
        const int r = wr + mi * 32 + l31;
        af[mi] = *(const bf16x8*)(As + r * 128 + (cb ^ ((r & 7) << 4)));
      }
#pragma unroll
      for (int ni = 0; ni < 2; ++ni) {
        const int r = wc + ni * 32 + l31;
        bw[ni] = *(const bf16x8*)(Bs + r * 128 + (cb ^ ((r & 7) << 4)));
      }
#pragma unroll
      for (int mi = 0; mi < 2; ++mi)
#pragma unroll
        for (int ni = 0; ni < 2; ++ni)
          acc[mi][ni] = __builtin_amdgcn_mfma_f32_32x32x16_bf16(af[mi], bw[ni], acc[mi][ni], 0, 0, 0);
    }
    __syncthreads();
  }

  // C layout (m101): col = lane&31, row = (reg&3) + 8*(reg>>2) + 4*(lane>>5)
#pragma unroll
  for (int mi = 0; mi < 2; ++mi)
#pragma unroll
    for (int ni = 0; ni < 2; ++ni)
#pragma unroll
      for (int reg = 0; reg < 16; ++reg) {
        const int m = bm + wr + mi * 32 + (reg & 3) + 8 * (reg >> 2) + 4 * hi;
        const int n = bn + wc + ni * 32 + l31;
        float x = acc[mi][ni][reg];
        const int nb = m >> 13;           // /8192
        const int l  = m & 8191;
        const int h  = n >> 6;
        if (MODE == 0) {
          x = sp_(sp_(x));
          const int d = n & 63;
          out[(((size_t)(nb * 8 + h) * 8192 + l) << 6) + d] = f2bf(x);
        } else {
          const int e = n & 63;
          const int cc = l >> 6, s2 = l & 63;
          out[(((size_t)((nb * 8 + h) * 128 + cc) * 64 + e) << 6) + s2] = f2bf(x);
        }
      }
}

// Per (nh, chunk): ST[e][d] = sum_s Vt[e][s]*K[s][d] via MFMA (in-LDS K transpose); z[d] = sum_s K[s][d]
__global__ __launch_bounds__(256, 4) void chunk_sums(const unsigned short* __restrict__ kb,
                                                     const unsigned short* __restrict__ vt,
                                                     char* __restrict__ S) {
  const int b  = blockIdx.x;          // nh*128 + c
  const int nh = b >> 7, c = b & 127;
  __shared__ char Kt[8192];    // [d][s] bf16, XOR-swizzled rows
  __shared__ char STs[8192];   // [e][d] bf16, linear
  const int tid = threadIdx.x, lane = tid & 63, wave = tid >> 6;
  const int l15 = lane & 15, lg = lane >> 4;
  const unsigned short* kch = kb + ((size_t)(nh * L_SEQ + c * 64) << 6);
  const unsigned short* vch = vt + ((size_t)b << 12);

  // transpose K chunk [s][d] -> Kt[d][s] (swizzled)
  {
    const int s = tid >> 2, d0 = (tid & 3) << 4;
    u16x8 a = *(const u16x8*)(kch + s * 64 + d0);
    u16x8 bb = *(const u16x8*)(kch + s * 64 + d0 + 8);
#pragma unroll
    for (int i = 0; i < 8; ++i) {
      const int d = d0 + i;
      *(unsigned short*)(Kt + d * 128 + ((2 * s) ^ ((d & 7) << 4))) = a[i];
    }
#pragma unroll
    for (int i = 0; i < 8; ++i) {
      const int d = d0 + 8 + i;
      *(unsigned short*)(Kt + d * 128 + ((2 * s) ^ ((d & 7) << 4))) = bb[i];
    }
  }
  __syncthreads();

  // MFMA: wave w -> e-rows 16w..16w+15 ; ST[e][d] = sum_s Vt[e][s]*Kt[d][s]
  f32x4 acc[4] = {};
#pragma unroll
  for (int kk = 0; kk < 2; ++kk) {
    bf16x8 av = *(const bf16x8*)(vch + (wave * 16 + l15) * 64 + kk * 32 + lg * 8);
#pragma unroll
    for (int ni = 0; ni < 4; ++ni) {
      const int d = ni * 16 + l15;
      bf16x8 bk = *(const bf16x8*)(Kt + d * 128 + ((kk * 64 + lg * 16) ^ ((d & 7) << 4)));
      acc[ni] = __builtin_amdgcn_mfma_f32_16x16x32_bf16(av, bk, acc[ni], 0, 0, 0);
    }
  }

  char* rec = S + (size_t)b * RECB;

  // z[d] = sum_s K[s][d] from Kt rows (f32)
  if (tid < 64) {
    float z = 0.f;
#pragma unroll
    for (int kk = 0; kk < 8; ++kk) {
      bf16x8 kv = *(const bf16x8*)(Kt + tid * 128 + ((kk * 16) ^ ((tid & 7) << 4)));
#pragma unroll
      for (int i = 0; i < 8; ++i) z += bf2f(kv[i]);
    }
    *(float*)(rec + 8192 + tid * 4) = z;
  }

  // stage ST to LDS (bf16), then coalesced copy-out
#pragma unroll
  for (int ni = 0; ni < 4; ++ni)
#pragma unroll
    for (int j = 0; j < 4; ++j) {
      const int e = wave * 16 + lg * 4 + j, d = ni * 16 + l15;
      *(unsigned short*)(STs + e * 128 + d * 2) = f2bf(acc[ni][j]);
    }
  __syncthreads();
  {
    const int off = tid * 32;
    *(u16x8*)(rec + off)      = *(const u16x8*)(STs + off);
    *(u16x8*)(rec + off + 16) = *(const u16x8*)(STs + off + 16);
  }
}

// Exclusive prefix over 128 chunks, in place. ST: bf16 payload, f32 accum (paired); z: f32.
__global__ void scan_chunks(char* __restrict__ S) {
  const int g = blockIdx.x * 256 + threadIdx.x;
  if (g < 65536) {                       // 32 nh * 2048 bf16-pairs
    const int nh = g >> 11, pr = g & 2047;
    char* p = S + (size_t)nh * NCHUNK * RECB + pr * 4;
    float a0 = 0.f, a1 = 0.f;
    for (int c = 0; c < NCHUNK; ++c) {
      const unsigned int u = *(unsigned int*)p;
      const float t0 = bf2f((unsigned short)(u & 0xffff));
      const float t1 = bf2f((unsigned short)(u >> 16));
      *(unsigned int*)p = (unsigned int)f2bf(a0) | ((unsigned int)f2bf(a1) << 16);
      a0 += t0; a1 += t1;
      p += RECB;
    }
  } else if (g < 67584) {                // 32 nh * 64 z floats
    const int idx = g - 65536;
    const int nh = idx >> 6, d = idx & 63;
    char* p = S + (size_t)nh * NCHUNK * RECB + 8192 + d * 4;
    float a = 0.f;
    for (int c = 0; c < NCHUNK; ++c) {
      const float t = *(float*)p; *(float*)p = a; a += t; p += RECB;
    }
  }
}

__global__ __launch_bounds__(256, 2) void attn_out(const unsigned short* __restrict__ qb,
                                                   const unsigned short* __restrict__ kb,
                                                   const unsigned short* __restrict__ vt,
                                                   const char* __restrict__ S,
                                                   float* __restrict__ out) {
  const int b  = blockIdx.x;
  const int nh = b >> 7, c = b & 127;
  const int nb = nh >> 3, h = nh & 7;
  __shared__ char Qs[8192], Ks[8192], Vs[8192], STs[8192], Ps[8192];
  __shared__ float zsh[64], dzh[64];
  const int tid = threadIdx.x, lane = tid & 63, wave = tid >> 6;
  const int l15 = lane & 15, lg = lane >> 4;

  const char* qch = (const char*)(qb + ((size_t)(nh * L_SEQ + c * 64) << 6));
  const char* kch = (const char*)(kb + ((size_t)(nh * L_SEQ + c * 64) << 6));
  const char* vch = (const char*)(vt + ((size_t)b << 12));
  const char* rb  = S + (size_t)b * RECB;

#pragma unroll
  for (int it = 0; it < 2; ++it) {
    const int p  = wave * 2048 + it * 1024 + lane * 16;
    const int r  = p >> 7;
    const int cb = (p & 127) ^ ((r & 7) << 4);
    const int src = r * 128 + cb;
    gll16(qch + src, Qs + wave * 2048 + it * 1024);
    gll16(kch + src, Ks + wave * 2048 + it * 1024);
    gll16(vch + src, Vs + wave * 2048 + it * 1024);
    gll16(rb + src,  STs + wave * 2048 + it * 1024);
  }
  if (tid < 64) zsh[tid] = *(const float*)(rb + 8192 + tid * 4);
  __syncthreads();

  // den_qz[t] = sum_d Q[t][d]*z_prev[d]
  {
    const int t = tid >> 2, p4 = tid & 3;
    float dq = 0.f;
#pragma unroll
    for (int half = 0; half < 2; ++half) {
      const int d0 = p4 * 16 + half * 8;
      const int cb = (d0 * 2) ^ ((t & 7) << 4);
      u16x8 qv = *(const u16x8*)(Qs + t * 128 + cb);
#pragma unroll
      for (int i = 0; i < 8; ++i) dq += bf2f(qv[i]) * zsh[d0 + i];
    }
    dq += __shfl_xor(dq, 1);
    dq += __shfl_xor(dq, 2);
    if (p4 == 0) dzh[t] = dq;
  }
  __syncthreads();

  // Phase 1: A = Q K^T (wave w owns rows 16w..16w+15)
  f32x4 accA[4] = {};
#pragma unroll
  for (int kk = 0; kk < 2; ++kk) {
    const int cb = kk * 64 + lg * 16;
    const int rq = wave * 16 + l15;
    bf16x8 aq = *(const bf16x8*)(Qs + rq * 128 + (cb ^ ((rq & 7) << 4)));
#pragma unroll
    for (int ni = 0; ni < 4; ++ni) {
      const int rk = ni * 16 + l15;
      bf16x8 bk = *(const bf16x8*)(Ks + rk * 128 + (cb ^ ((rk & 7) << 4)));
      accA[ni] = __builtin_amdgcn_mfma_f32_16x16x32_bf16(aq, bk, accA[ni], 0, 0, 0);
    }
  }

  // mask causal, rowsum (on bf16-rounded P for num/den consistency), write P
  float den4[4];
#pragma unroll
  for (int j = 0; j < 4; ++j) {
    const int t = wave * 16 + lg * 4 + j;
    float rs = 0.f;
#pragma unroll
    for (int ni = 0; ni < 4; ++ni) {
      const int s = ni * 16 + l15;
      const float v = (s <= t) ? accA[ni][j] : 0.f;
      const unsigned short pb = f2bf(v);
      rs += bf2f(pb);
      *(unsigned short*)(Ps + t * 128 + ((s * 2) ^ ((t & 7) << 4))) = pb;
    }
    rs += __shfl_xor(rs, 1);
    rs += __shfl_xor(rs, 2);
    rs += __shfl_xor(rs, 4);
    rs += __shfl_xor(rs, 8);
    den4[j] = rs + dzh[t];
  }
  __syncthreads();

  // Phase 2: num = P V + Q S_prev  (both B-operands bf16 rows, identical addressing)
  f32x4 accO[4] = {};
#pragma unroll
  for (int kk = 0; kk < 2; ++kk) {
    const int cb = kk * 64 + lg * 16;
    const int rp = wave * 16 + l15;
    bf16x8 ap = *(const bf16x8*)(Ps + rp * 128 + (cb ^ ((rp & 7) << 4)));
    bf16x8 aq = *(const bf16x8*)(Qs + rp * 128 + (cb ^ ((rp & 7) << 4)));
#pragma unroll
    for (int ni = 0; ni < 4; ++ni) {
      const int rv = ni * 16 + l15;
      bf16x8 bv = *(const bf16x8*)(Vs + rv * 128 + (cb ^ ((rv & 7) << 4)));
      bf16x8 bs = *(const bf16x8*)(STs + rv * 128 + (cb ^ ((rv & 7) << 4)));
      accO[ni] = __builtin_amdgcn_mfma_f32_16x16x32_bf16(ap, bv, accO[ni], 0, 0, 0);
      accO[ni] = __builtin_amdgcn_mfma_f32_16x16x32_bf16(aq, bs, accO[ni], 0, 0, 0);
    }
  }

#pragma unroll
  for (int ni = 0; ni < 4; ++ni) {
    const int e = ni * 16 + l15;
#pragma unroll
    for (int j = 0; j < 4; ++j) {
      const int t = wave * 16 + lg * 4 + j;
      out[((size_t)(nb * L_SEQ + c * 64 + t) << 9) + h * 64 + e] = accO[ni][j] / den4[j];
    }
  }
}

extern "C" void kernel_launch(void* const* d_in, const int* in_sizes, int n_in,
                              void* d_out, int out_size, void* d_ws, size_t ws_size,
                              hipStream_t stream) {
  (void)in_sizes; (void)n_in; (void)out_size; (void)ws_size;
  const float* query = (const float*)d_in[0];
  const float* key   = (const float*)d_in[1];
  const float* Wq    = (const float*)d_in[2];
  const float* Wk    = (const float*)d_in[3];
  const float* Wv    = (const float*)d_in[4];
  float* out = (float*)d_out;
  char* ws = (char*)d_ws;

  unsigned short* qb  = (unsigned short*)(ws);              // 33,554,432 B  (nh,l,d) bf16
  unsigned short* kb  = (unsigned short*)(ws + 33554432);   // 33,554,432 B
  unsigned short* vt  = (unsigned short*)(ws + 67108864);   // 33,554,432 B  (nh,c,e,s) bf16
  unsigned short* qbf = (unsigned short*)(ws + 100663296);  // 33,554,432 B  (dead after GEMMs)
  unsigned short* kbf = (unsigned short*)(ws + 134217728);  // 33,554,432 B  (dead after GEMMs)
  char*           Ssum = ws + 100663296;                    // 34,603,008 B  (aliased over qbf/kbf)
  unsigned short* wqb = (unsigned short*)(ws + 168820736);
  unsigned short* wkb = (unsigned short*)(ws + 169345024);
  unsigned short* wvb = (unsigned short*)(ws + 169869312);  // end: 170,393,600 B

  cvt_all<<<dim3(2048), dim3(256), 0, stream>>>(query, key, Wq, Wk, Wv, qbf, kbf, wqb, wkb, wvb);

  dim3 gg(256, 4);
  gemm_proj<0><<<gg, dim3(256), 0, stream>>>(qbf, wqb, qb);
  gemm_proj<0><<<gg, dim3(256), 0, stream>>>(kbf, wkb, kb);
  gemm_proj<1><<<gg, dim3(256), 0, stream>>>(kbf, wvb, vt);

  chunk_sums<<<dim3(4096), dim3(256), 0, stream>>>(kb, vt, Ssum);
  scan_chunks<<<dim3(264), dim3(256), 0, stream>>>(Ssum);
  attn_out<<<dim3(4096), dim3(256), 0, stream>>>(qb, kb, vt, Ssum, out);
}